// Round 10
// baseline (424.974 us; speedup 1.0000x reference)
//
#include <hip/hip_runtime.h>
#include <hip/hip_bf16.h>

// Problem constants
#define PN 16384
#define PZ 100
#define PE 400
#define PM0 4000
#define PM1 2000
#define KP 128            // packed K: [0,100)=theta/topic, [100,104)=onehot/bias, rest 0
#define SEG1ROW 4096      // B2T row base of segment 1
#define MROWS 6144        // 4096 (seg0 pad) + 2048 (seg1 pad)

typedef __attribute__((ext_vector_type(8))) _Float16 half8v;
typedef __attribute__((ext_vector_type(4))) float floatx4;
typedef __attribute__((ext_vector_type(4))) unsigned int uint4v;

// ---------------------------------------------------------------------------
// topic v2: one block per 64 B2T rows (covers pads). Computes topic, appends
// f16 bias columns (k=100..103) and zero k-pad, writes full rows coalesced.
// grid: 96 blocks (64 seg0 + 32 seg1), 256 threads.
// ---------------------------------------------------------------------------
__global__ __launch_bounds__(256) void topic_kernel(
    const float* __restrict__ alpha0, const float* __restrict__ alpha1,
    const float* __restrict__ beta,
    const float* __restrict__ bias0, const float* __restrict__ bias1,
    _Float16* __restrict__ b2t)
{
    __shared__ __align__(16) char lds[64 * 201 * 4];   // union: f32 alpha / f16 stage
    float* sAl = (float*)lds;                          // [64][201]
    _Float16* st = (_Float16*)lds;                     // [64][128]

    const int seg = (blockIdx.x >= 64);
    const int bt  = seg ? (blockIdx.x - 64) : blockIdx.x;
    const float* alpha = seg ? alpha1 : alpha0;
    const float* bias  = seg ? bias1 : bias0;
    const int Mse = seg ? PM1 : PM0;
    const int rowbase = (seg ? SEG1ROW : 0) + bt * 64;
    const int m0 = bt * 64;

    const int tid = threadIdx.x;
    const int ml = tid & 63;      // m within panel
    const int zt = tid >> 6;      // 0..3, owns z = zt*25 .. +25
    const int m  = m0 + ml;
    const bool mvalid = (m < Mse);

    float acc[25];
    #pragma unroll
    for (int j = 0; j < 25; ++j) acc[j] = 0.f;

    for (int ec = 0; ec < 2; ++ec) {
        #pragma unroll
        for (int l = 0; l < 50; ++l) {     // 64 rows x 200 e / 256 thr
            int idx = tid + l * 256;
            int mr = idx / 200;
            int e  = idx - mr * 200;
            int mm = m0 + mr;
            sAl[mr * 201 + e] = (mm < Mse) ? alpha[(size_t)mm * PE + ec * 200 + e] : 0.f;
        }
        __syncthreads();
        const float* bz = beta + (size_t)(zt * 25) * PE + ec * 200;  // wave-uniform
        for (int e = 0; e < 200; ++e) {
            float a = sAl[ml * 201 + e];
            #pragma unroll
            for (int j = 0; j < 25; ++j)
                acc[j] = fmaf(bz[(size_t)j * PE + e], a, acc[j]);
        }
        __syncthreads();
    }

    // stage f16 rows: topic k=0..99
    #pragma unroll
    for (int j = 0; j < 25; ++j)
        st[ml * 128 + zt * 25 + j] = mvalid ? (_Float16)acc[j] : (_Float16)0.f;
    // bias cols k=100..103 (256 thr = 64 m x 4 d)
    {
        int mr = tid >> 2, d = tid & 3;
        int mm = m0 + mr;
        st[mr * 128 + 100 + d] =
            (mm < Mse) ? (_Float16)bias[(size_t)d * Mse + mm] : (_Float16)0.f;
    }
    // k-pad 104..127 zero
    for (int idx = tid; idx < 64 * 24; idx += 256) {
        int r = idx / 24, k = 104 + idx - (idx / 24) * 24;
        st[r * 128 + k] = (_Float16)0.f;
    }
    __syncthreads();

    // coalesced writeout: 64 rows x 256 B = 16 KB
    #pragma unroll
    for (int it = 0; it < 4; ++it) {
        int off = it * 4096 + tid * 16;
        uint4v v = *(const uint4v*)((const char*)st + off);
        *(uint4v*)((char*)b2t + (size_t)rowbase * 256 + off) = v;
    }
}

// ---------------------------------------------------------------------------
// Fused GEMM + LSE + writeout, v4: bias folded into MFMA via one-hot K slots.
// 512 blocks x 512 threads (8 waves); block = 32 rows x both segments.
// B fragments direct from L2 to registers, x2-unrolled manual prefetch.
// ---------------------------------------------------------------------------
__global__ __launch_bounds__(512, 4) void fused_kernel(
    const float* __restrict__ theta,
    const _Float16* __restrict__ B2T,
    const int* __restrict__ dom,
    float* __restrict__ out0, float* __restrict__ out1)
{
    __shared__ __align__(1024) char sA[32 * 256];   // 8 KB swizzled A panel
    __shared__ float smx[8][32];
    __shared__ float sms[8][32];
    __shared__ float slse[32];

    const int tid = threadIdx.x;
    const int w   = tid >> 6;     // 0..7
    const int ll  = tid & 63;
    const int g   = ll >> 4;      // 0..3
    const int c   = ll & 15;      // 0..15
    const int n0  = blockIdx.x * 32;

    // ---- stage A: theta f32 -> f16 + one-hot domain at k=100..103 ----
    {
        int row  = tid >> 4;          // 0..31
        int slot = tid & 15;
        const float* tr = theta + (size_t)(n0 + row) * PZ + slot * 8;
        half8v h = (half8v)(_Float16)0.f;
        if (slot < 12) {
            float4 lo = *(const float4*)tr;
            float4 hi = *(const float4*)(tr + 4);
            h[0] = (_Float16)lo.x; h[1] = (_Float16)lo.y;
            h[2] = (_Float16)lo.z; h[3] = (_Float16)lo.w;
            h[4] = (_Float16)hi.x; h[5] = (_Float16)hi.y;
            h[6] = (_Float16)hi.z; h[7] = (_Float16)hi.w;
        } else if (slot == 12) {
            float4 lo = *(const float4*)tr;   // k = 96..99
            h[0] = (_Float16)lo.x; h[1] = (_Float16)lo.y;
            h[2] = (_Float16)lo.z; h[3] = (_Float16)lo.w;
            int d = dom[n0 + row];            // k=100..103: one-hot(dom)
            h[4] = (_Float16)(d == 0 ? 1.f : 0.f);
            h[5] = (_Float16)(d == 1 ? 1.f : 0.f);
            h[6] = (_Float16)(d == 2 ? 1.f : 0.f);
            h[7] = (_Float16)(d == 3 ? 1.f : 0.f);
        }
        *(half8v*)(sA + row * 256 + ((slot ^ (row & 7)) * 16)) = h;
    }
    __syncthreads();

    // ---- A fragments -> registers ----
    half8v aF[2][4];
    #pragma unroll
    for (int mi = 0; mi < 2; ++mi) {
        int row = mi * 16 + c;
        #pragma unroll
        for (int kb = 0; kb < 4; ++kb) {
            int slot = (kb * 4 + g) ^ (row & 7);
            aF[mi][kb] = *(const half8v*)(sA + row * 256 + slot * 16);
        }
    }

    const int mbase = w * 16 + c;

    for (int seg = 0; seg < 2; ++seg) {
        const int Mse = seg ? PM1 : PM0;
        const int NT  = seg ? 16 : 32;                 // 128-col tiles (even)
        const _Float16* Bseg = B2T + (size_t)(seg ? SEG1ROW : 0) * KP;
        float* out = seg ? out1 : out0;

        const _Float16* bp0 = Bseg + (size_t)mbase * KP;   // lane's B row
        const size_t TSTEP = (size_t)128 * KP;

        float mx_[2][4], sm_[2][4];
        #pragma unroll
        for (int mi = 0; mi < 2; ++mi)
            #pragma unroll
            for (int i = 0; i < 4; ++i) { mx_[mi][i] = -3.0e38f; sm_[mi][i] = 0.f; }

        // ---- helpers ----
        auto loadB = [&](half8v (&bf)[4], const _Float16* p) {
            #pragma unroll
            for (int kb = 0; kb < 4; ++kb)
                bf[kb] = *(const half8v*)(p + kb * 32 + g * 8);
        };
        auto mfma8 = [&](half8v (&bf)[4], floatx4& a0, floatx4& a1) {
            a0 = (floatx4){0.f, 0.f, 0.f, 0.f};
            a1 = (floatx4){0.f, 0.f, 0.f, 0.f};
            #pragma unroll
            for (int kb = 0; kb < 4; ++kb) {
                a0 = __builtin_amdgcn_mfma_f32_16x16x32_f16(aF[0][kb], bf[kb], a0, 0, 0, 0);
                a1 = __builtin_amdgcn_mfma_f32_16x16x32_f16(aF[1][kb], bf[kb], a1, 0, 0, 0);
            }
        };
        auto stats_step = [&](floatx4& a0, floatx4& a1, int t) {
            const bool mv = (t * 128 + mbase) < Mse;
            float vv[2][4];
            float gm = -3.0e38f;
            #pragma unroll
            for (int mi = 0; mi < 2; ++mi)
                #pragma unroll
                for (int i = 0; i < 4; ++i) {
                    float v = mv ? (mi ? a1[i] : a0[i]) : -1.0e30f;
                    vv[mi][i] = v;
                    gm = fmaxf(gm, v - mx_[mi][i]);
                }
            if (gm <= 8.0f) {
                #pragma unroll
                for (int mi = 0; mi < 2; ++mi)
                    #pragma unroll
                    for (int i = 0; i < 4; ++i)
                        sm_[mi][i] += __expf(vv[mi][i] - mx_[mi][i]);
            } else {
                #pragma unroll
                for (int mi = 0; mi < 2; ++mi)
                    #pragma unroll
                    for (int i = 0; i < 4; ++i) {
                        float v  = vv[mi][i];
                        float nm = fmaxf(mx_[mi][i], v);
                        sm_[mi][i] = sm_[mi][i] * __expf(mx_[mi][i] - nm) + __expf(v - nm);
                        mx_[mi][i] = nm;
                    }
            }
        };

        // =========== stats sweep, x2-unrolled prefetch ===========
        {
            half8v bA[4], bB[4];
            floatx4 a0, a1;
            const _Float16* bp = bp0;
            loadB(bA, bp);
            for (int t = 0; t < NT; t += 2) {
                loadB(bB, bp + TSTEP);
                mfma8(bA, a0, a1);
                stats_step(a0, a1, t);
                if (t + 2 < NT) loadB(bA, bp + 2 * TSTEP);
                mfma8(bB, a0, a1);
                stats_step(a0, a1, t + 1);
                bp += 2 * TSTEP;
            }
        }

        // =========== reduce -> per-row LSE ===========
        #pragma unroll
        for (int mi = 0; mi < 2; ++mi) {
            #pragma unroll
            for (int i = 0; i < 4; ++i) {
                float m_ = mx_[mi][i], s_ = sm_[mi][i];
                #pragma unroll
                for (int msk = 1; msk < 16; msk <<= 1) {
                    float mo = __shfl_xor(m_, msk);
                    float so = __shfl_xor(s_, msk);
                    float nm = fmaxf(m_, mo);
                    s_ = s_ * __expf(m_ - nm) + so * __expf(mo - nm);
                    m_ = nm;
                }
                if (c == 0) {
                    int row = mi * 16 + 4 * g + i;
                    smx[w][row] = m_;
                    sms[w][row] = s_;
                }
            }
        }
        __syncthreads();
        if (tid < 32) {
            float m_ = smx[0][tid], s_ = sms[0][tid];
            #pragma unroll
            for (int wv = 1; wv < 8; ++wv) {
                float mo = smx[wv][tid];
                float so = sms[wv][tid];
                float nm = fmaxf(m_, mo);
                s_ = s_ * __expf(m_ - nm) + so * __expf(mo - nm);
                m_ = nm;
            }
            slse[tid] = m_ + __logf(s_);
        }
        __syncthreads();
        float lse_[2][4];
        #pragma unroll
        for (int mi = 0; mi < 2; ++mi)
            #pragma unroll
            for (int i = 0; i < 4; ++i)
                lse_[mi][i] = slse[mi * 16 + 4 * g + i];
        __syncthreads();   // protect slse before next seg reuses it

        // =========== write sweep (recompute), x2-unrolled prefetch ===========
        {
            // per-row output pointers (pointer-increment addressing)
            float* op[2][4];
            #pragma unroll
            for (int mi = 0; mi < 2; ++mi)
                #pragma unroll
                for (int i = 0; i < 4; ++i)
                    op[mi][i] = out + (size_t)(n0 + mi * 16 + 4 * g + i) * Mse + mbase;

            auto write_step = [&](floatx4& a0, floatx4& a1, int t) {
                const bool mv = (t * 128 + mbase) < Mse;
                if (mv) {
                    #pragma unroll
                    for (int mi = 0; mi < 2; ++mi)
                        #pragma unroll
                        for (int i = 0; i < 4; ++i) {
                            float o = (mi ? a1[i] : a0[i]) - lse_[mi][i];
                            __builtin_nontemporal_store(o, op[mi][i]);
                        }
                }
                #pragma unroll
                for (int mi = 0; mi < 2; ++mi)
                    #pragma unroll
                    for (int i = 0; i < 4; ++i)
                        op[mi][i] += 128;
            };

            half8v bA[4], bB[4];
            floatx4 a0, a1;
            const _Float16* bp = bp0;
            loadB(bA, bp);
            for (int t = 0; t < NT; t += 2) {
                loadB(bB, bp + TSTEP);
                mfma8(bA, a0, a1);
                write_step(a0, a1, t);
                if (t + 2 < NT) loadB(bA, bp + 2 * TSTEP);
                mfma8(bB, a0, a1);
                write_step(a0, a1, t + 1);
                bp += 2 * TSTEP;
            }
        }
    }
}

// ---------------------------------------------------------------------------
extern "C" void kernel_launch(void* const* d_in, const int* in_sizes, int n_in,
                              void* d_out, int out_size, void* d_ws, size_t ws_size,
                              hipStream_t stream) {
    const float* theta  = (const float*)d_in[0];
    const float* alpha0 = (const float*)d_in[1];
    const float* alpha1 = (const float*)d_in[2];
    const float* beta   = (const float*)d_in[3];
    const float* bias0  = (const float*)d_in[4];
    const float* bias1  = (const float*)d_in[5];
    const int*   dom    = (const int*)d_in[6];

    float* out0 = (float*)d_out;
    float* out1 = out0 + (size_t)PN * PM0;

    _Float16* B2T = (_Float16*)d_ws;   // [MROWS][KP] f16, 1.57 MB (fully written)

    // 1. topic + bias + pads -> B2T (full rows, coalesced; no fill needed)
    topic_kernel<<<96, 256, 0, stream>>>(alpha0, alpha1, beta, bias0, bias1, B2T);

    // 2. fused GEMM(+bias via one-hot K) + LSE + writeout
    fused_kernel<<<PN / 32, 512, 0, stream>>>(theta, B2T, dom, out0, out1);
}

// Round 11
// 261.671 us; speedup vs baseline: 1.6241x; 1.6241x over previous
//
#include <hip/hip_runtime.h>
#include <hip/hip_bf16.h>

// Problem constants
#define PN 16384
#define PZ 100
#define PE 400
#define PM0 4000
#define PM1 2000
#define KP 128            // packed K: [0,100)=theta/topic, [100,104)=onehot/bias, rest 0
#define SEG1ROW 4096      // B2T row base of segment 1
#define MROWS 6144        // 4096 (seg0 pad) + 2048 (seg1 pad)

typedef __attribute__((ext_vector_type(8))) _Float16 half8v;
typedef __attribute__((ext_vector_type(4))) float floatx4;
typedef __attribute__((ext_vector_type(4))) unsigned int uint4v;

// ---------------------------------------------------------------------------
// zero-fill whole B2T (pads + k-slop deterministically zero)
// ---------------------------------------------------------------------------
__global__ __launch_bounds__(256) void fill_kernel(uint4v* __restrict__ p, int n16)
{
    int i = blockIdx.x * 256 + threadIdx.x;
    if (i < n16) p[i] = (uint4v){0u, 0u, 0u, 0u};
}

// ---------------------------------------------------------------------------
// topic v5: grid (96,5); block = 64 m x 20 z; thread = 1 m x 5 z.
// BOTH alpha chunk and beta chunk staged in LDS (beta in registers was the
// round-10 trap: not provably wave-uniform -> per-lane vector loads).
// e processed in 4 chunks of 100 -> 34 KB LDS.
// ---------------------------------------------------------------------------
__global__ __launch_bounds__(256) void topic_kernel(
    const float* __restrict__ alpha0, const float* __restrict__ alpha1,
    const float* __restrict__ beta, _Float16* __restrict__ b2t)
{
    __shared__ float sAl[64][101];   // 25.9 KB
    __shared__ float sBt[20][100];   // 8 KB

    const int seg = (blockIdx.x >= 64);
    const int tile = seg ? (blockIdx.x - 64) : blockIdx.x;
    const float* alpha = seg ? alpha1 : alpha0;
    const int Mse = seg ? PM1 : PM0;
    const int rowbase = (seg ? SEG1ROW : 0) + tile * 64;
    const int m0 = tile * 64;

    const int tid = threadIdx.x;
    const int ml = tid & 63;
    const int zt = tid >> 6;              // wave id 0..3
    const int z0 = blockIdx.y * 20;       // block z-base

    float acc[5] = {0.f, 0.f, 0.f, 0.f, 0.f};

    for (int ec = 0; ec < 4; ++ec) {
        // stage alpha chunk: 64 m x 100 e
        #pragma unroll
        for (int l = 0; l < 25; ++l) {
            int idx = tid + l * 256;
            int mr = idx / 100;
            int e  = idx - mr * 100;
            int mm = m0 + mr;
            sAl[mr][e] = (mm < Mse) ? alpha[(size_t)mm * PE + ec * 100 + e] : 0.f;
        }
        // stage beta chunk: 20 z x 100 e
        for (int idx = tid; idx < 2000; idx += 256) {
            int zr = idx / 100;
            int e  = idx - zr * 100;
            sBt[zr][e] = beta[(size_t)(z0 + zr) * PE + ec * 100 + e];
        }
        __syncthreads();

        #pragma unroll 2
        for (int e = 0; e < 100; ++e) {
            float a = sAl[ml][e];
            #pragma unroll
            for (int zi = 0; zi < 5; ++zi)
                acc[zi] = fmaf(sBt[zt * 5 + zi][e], a, acc[zi]);
        }
        __syncthreads();
    }

    int m = m0 + ml;
    if (m < Mse) {
        #pragma unroll
        for (int zi = 0; zi < 5; ++zi)
            b2t[(size_t)(rowbase + ml) * KP + (z0 + zt * 5 + zi)] = (_Float16)acc[zi];
    }
}

// ---------------------------------------------------------------------------
// bias cols k=100..103 of B2T (one thread per row)
// ---------------------------------------------------------------------------
__global__ __launch_bounds__(256) void bias_kernel(
    const float* __restrict__ bias0, const float* __restrict__ bias1,
    _Float16* __restrict__ b2t)
{
    int row = blockIdx.x * 256 + threadIdx.x;
    if (row >= MROWS) return;
    int seg = (row >= SEG1ROW);
    int m = row - (seg ? SEG1ROW : 0);
    int Mse = seg ? PM1 : PM0;
    const float* bias = seg ? bias1 : bias0;
    if (m < Mse) {
        #pragma unroll
        for (int d = 0; d < 4; ++d)
            b2t[(size_t)row * KP + 100 + d] = (_Float16)bias[(size_t)d * Mse + m];
    }
}

// ---------------------------------------------------------------------------
// Fused GEMM + LSE + writeout, v4 (unchanged from round 10 — measured ~170us):
// bias folded into MFMA via one-hot K slots; 512 blocks x 512 threads;
// B fragments direct from L2 to registers, x2-unrolled manual prefetch.
// ---------------------------------------------------------------------------
__global__ __launch_bounds__(512, 4) void fused_kernel(
    const float* __restrict__ theta,
    const _Float16* __restrict__ B2T,
    const int* __restrict__ dom,
    float* __restrict__ out0, float* __restrict__ out1)
{
    __shared__ __align__(1024) char sA[32 * 256];   // 8 KB swizzled A panel
    __shared__ float smx[8][32];
    __shared__ float sms[8][32];
    __shared__ float slse[32];

    const int tid = threadIdx.x;
    const int w   = tid >> 6;     // 0..7
    const int ll  = tid & 63;
    const int g   = ll >> 4;      // 0..3
    const int c   = ll & 15;      // 0..15
    const int n0  = blockIdx.x * 32;

    // ---- stage A: theta f32 -> f16 + one-hot domain at k=100..103 ----
    {
        int row  = tid >> 4;          // 0..31
        int slot = tid & 15;
        const float* tr = theta + (size_t)(n0 + row) * PZ + slot * 8;
        half8v h = (half8v)(_Float16)0.f;
        if (slot < 12) {
            float4 lo = *(const float4*)tr;
            float4 hi = *(const float4*)(tr + 4);
            h[0] = (_Float16)lo.x; h[1] = (_Float16)lo.y;
            h[2] = (_Float16)lo.z; h[3] = (_Float16)lo.w;
            h[4] = (_Float16)hi.x; h[5] = (_Float16)hi.y;
            h[6] = (_Float16)hi.z; h[7] = (_Float16)hi.w;
        } else if (slot == 12) {
            float4 lo = *(const float4*)tr;   // k = 96..99
            h[0] = (_Float16)lo.x; h[1] = (_Float16)lo.y;
            h[2] = (_Float16)lo.z; h[3] = (_Float16)lo.w;
            int d = dom[n0 + row];            // k=100..103: one-hot(dom)
            h[4] = (_Float16)(d == 0 ? 1.f : 0.f);
            h[5] = (_Float16)(d == 1 ? 1.f : 0.f);
            h[6] = (_Float16)(d == 2 ? 1.f : 0.f);
            h[7] = (_Float16)(d == 3 ? 1.f : 0.f);
        }
        *(half8v*)(sA + row * 256 + ((slot ^ (row & 7)) * 16)) = h;
    }
    __syncthreads();

    // ---- A fragments -> registers ----
    half8v aF[2][4];
    #pragma unroll
    for (int mi = 0; mi < 2; ++mi) {
        int row = mi * 16 + c;
        #pragma unroll
        for (int kb = 0; kb < 4; ++kb) {
            int slot = (kb * 4 + g) ^ (row & 7);
            aF[mi][kb] = *(const half8v*)(sA + row * 256 + slot * 16);
        }
    }

    const int mbase = w * 16 + c;

    for (int seg = 0; seg < 2; ++seg) {
        const int Mse = seg ? PM1 : PM0;
        const int NT  = seg ? 16 : 32;                 // 128-col tiles (even)
        const _Float16* Bseg = B2T + (size_t)(seg ? SEG1ROW : 0) * KP;
        float* out = seg ? out1 : out0;

        const _Float16* bp0 = Bseg + (size_t)mbase * KP;   // lane's B row
        const size_t TSTEP = (size_t)128 * KP;

        float mx_[2][4], sm_[2][4];
        #pragma unroll
        for (int mi = 0; mi < 2; ++mi)
            #pragma unroll
            for (int i = 0; i < 4; ++i) { mx_[mi][i] = -3.0e38f; sm_[mi][i] = 0.f; }

        // ---- helpers ----
        auto loadB = [&](half8v (&bf)[4], const _Float16* p) {
            #pragma unroll
            for (int kb = 0; kb < 4; ++kb)
                bf[kb] = *(const half8v*)(p + kb * 32 + g * 8);
        };
        auto mfma8 = [&](half8v (&bf)[4], floatx4& a0, floatx4& a1) {
            a0 = (floatx4){0.f, 0.f, 0.f, 0.f};
            a1 = (floatx4){0.f, 0.f, 0.f, 0.f};
            #pragma unroll
            for (int kb = 0; kb < 4; ++kb) {
                a0 = __builtin_amdgcn_mfma_f32_16x16x32_f16(aF[0][kb], bf[kb], a0, 0, 0, 0);
                a1 = __builtin_amdgcn_mfma_f32_16x16x32_f16(aF[1][kb], bf[kb], a1, 0, 0, 0);
            }
        };
        auto stats_step = [&](floatx4& a0, floatx4& a1, int t) {
            const bool mv = (t * 128 + mbase) < Mse;
            float vv[2][4];
            float gm = -3.0e38f;
            #pragma unroll
            for (int mi = 0; mi < 2; ++mi)
                #pragma unroll
                for (int i = 0; i < 4; ++i) {
                    float v = mv ? (mi ? a1[i] : a0[i]) : -1.0e30f;
                    vv[mi][i] = v;
                    gm = fmaxf(gm, v - mx_[mi][i]);
                }
            if (gm <= 8.0f) {
                #pragma unroll
                for (int mi = 0; mi < 2; ++mi)
                    #pragma unroll
                    for (int i = 0; i < 4; ++i)
                        sm_[mi][i] += __expf(vv[mi][i] - mx_[mi][i]);
            } else {
                #pragma unroll
                for (int mi = 0; mi < 2; ++mi)
                    #pragma unroll
                    for (int i = 0; i < 4; ++i) {
                        float v  = vv[mi][i];
                        float nm = fmaxf(mx_[mi][i], v);
                        sm_[mi][i] = sm_[mi][i] * __expf(mx_[mi][i] - nm) + __expf(v - nm);
                        mx_[mi][i] = nm;
                    }
            }
        };

        // =========== stats sweep, x2-unrolled prefetch ===========
        {
            half8v bA[4], bB[4];
            floatx4 a0, a1;
            const _Float16* bp = bp0;
            loadB(bA, bp);
            for (int t = 0; t < NT; t += 2) {
                loadB(bB, bp + TSTEP);
                mfma8(bA, a0, a1);
                stats_step(a0, a1, t);
                if (t + 2 < NT) loadB(bA, bp + 2 * TSTEP);
                mfma8(bB, a0, a1);
                stats_step(a0, a1, t + 1);
                bp += 2 * TSTEP;
            }
        }

        // =========== reduce -> per-row LSE ===========
        #pragma unroll
        for (int mi = 0; mi < 2; ++mi) {
            #pragma unroll
            for (int i = 0; i < 4; ++i) {
                float m_ = mx_[mi][i], s_ = sm_[mi][i];
                #pragma unroll
                for (int msk = 1; msk < 16; msk <<= 1) {
                    float mo = __shfl_xor(m_, msk);
                    float so = __shfl_xor(s_, msk);
                    float nm = fmaxf(m_, mo);
                    s_ = s_ * __expf(m_ - nm) + so * __expf(mo - nm);
                    m_ = nm;
                }
                if (c == 0) {
                    int row = mi * 16 + 4 * g + i;
                    smx[w][row] = m_;
                    sms[w][row] = s_;
                }
            }
        }
        __syncthreads();
        if (tid < 32) {
            float m_ = smx[0][tid], s_ = sms[0][tid];
            #pragma unroll
            for (int wv = 1; wv < 8; ++wv) {
                float mo = smx[wv][tid];
                float so = sms[wv][tid];
                float nm = fmaxf(m_, mo);
                s_ = s_ * __expf(m_ - nm) + so * __expf(mo - nm);
                m_ = nm;
            }
            slse[tid] = m_ + __logf(s_);
        }
        __syncthreads();
        float lse_[2][4];
        #pragma unroll
        for (int mi = 0; mi < 2; ++mi)
            #pragma unroll
            for (int i = 0; i < 4; ++i)
                lse_[mi][i] = slse[mi * 16 + 4 * g + i];
        __syncthreads();   // protect slse before next seg reuses it

        // =========== write sweep (recompute), x2-unrolled prefetch ===========
        {
            float* op[2][4];
            #pragma unroll
            for (int mi = 0; mi < 2; ++mi)
                #pragma unroll
                for (int i = 0; i < 4; ++i)
                    op[mi][i] = out + (size_t)(n0 + mi * 16 + 4 * g + i) * Mse + mbase;

            auto write_step = [&](floatx4& a0, floatx4& a1, int t) {
                const bool mv = (t * 128 + mbase) < Mse;
                if (mv) {
                    #pragma unroll
                    for (int mi = 0; mi < 2; ++mi)
                        #pragma unroll
                        for (int i = 0; i < 4; ++i) {
                            float o = (mi ? a1[i] : a0[i]) - lse_[mi][i];
                            __builtin_nontemporal_store(o, op[mi][i]);
                        }
                }
                #pragma unroll
                for (int mi = 0; mi < 2; ++mi)
                    #pragma unroll
                    for (int i = 0; i < 4; ++i)
                        op[mi][i] += 128;
            };

            half8v bA[4], bB[4];
            floatx4 a0, a1;
            const _Float16* bp = bp0;
            loadB(bA, bp);
            for (int t = 0; t < NT; t += 2) {
                loadB(bB, bp + TSTEP);
                mfma8(bA, a0, a1);
                write_step(a0, a1, t);
                if (t + 2 < NT) loadB(bA, bp + 2 * TSTEP);
                mfma8(bB, a0, a1);
                write_step(a0, a1, t + 1);
                bp += 2 * TSTEP;
            }
        }
    }
}

// ---------------------------------------------------------------------------
extern "C" void kernel_launch(void* const* d_in, const int* in_sizes, int n_in,
                              void* d_out, int out_size, void* d_ws, size_t ws_size,
                              hipStream_t stream) {
    const float* theta  = (const float*)d_in[0];
    const float* alpha0 = (const float*)d_in[1];
    const float* alpha1 = (const float*)d_in[2];
    const float* beta   = (const float*)d_in[3];
    const float* bias0  = (const float*)d_in[4];
    const float* bias1  = (const float*)d_in[5];
    const int*   dom    = (const int*)d_in[6];

    float* out0 = (float*)d_out;
    float* out1 = out0 + (size_t)PN * PM0;

    _Float16* B2T = (_Float16*)d_ws;   // [MROWS][KP] f16, 1.57 MB

    // 1. zero B2T (pads + unused k deterministically zero)
    {
        int n16 = MROWS * KP * 2 / 16;
        fill_kernel<<<(n16 + 255) / 256, 256, 0, stream>>>((uint4v*)B2T, n16);
    }

    // 2. topics (480 blocks, LDS-staged alpha AND beta) -> B2T k=0..99
    topic_kernel<<<dim3(96, 5), 256, 0, stream>>>(alpha0, alpha1, beta, B2T);

    // 3. bias cols k=100..103
    bias_kernel<<<MROWS / 256, 256, 0, stream>>>(bias0, bias1, B2T);

    // 4. fused GEMM(+bias via one-hot K) + LSE + writeout
    fused_kernel<<<PN / 32, 512, 0, stream>>>(theta, B2T, dom, out0, out1);
}